// Round 1
// baseline (1306.583 us; speedup 1.0000x reference)
//
#include <hip/hip_runtime.h>
#include <hip/hip_bf16.h>

#define NN 2000   // nodes
#define NP 2048   // padded
#define BB 8
#define HH 64
#define DD 16

typedef __hip_bfloat16 bf16;
typedef short bf16x8 __attribute__((ext_vector_type(8)));  // 8 bf16 in 4 VGPRs
typedef float f32x4 __attribute__((ext_vector_type(4)));

__device__ __forceinline__ float fast_sigmoid(float x) {
    return 1.0f / (1.0f + __expf(-x));
}
__device__ __forceinline__ float fast_tanh(float x) {
    float e = __expf(2.0f * x);           // inf-safe: x>>0 -> 1, x<<0 -> -1
    return 1.0f - 2.0f / (e + 1.0f);
}

// ---------------------------------------------------------------------------
// h = relu(z @ W_in^T + b_in); e1 = h@w1, e2 = h@w2.  One 64-thread wave per
// (b,n) row. W_in staged transposed in LDS (pad 65 -> conflict-free).
// ---------------------------------------------------------------------------
__global__ __launch_bounds__(64) void k_h(
        const float* __restrict__ z, const float* __restrict__ W_in,
        const float* __restrict__ b_in, const float* __restrict__ w1,
        const float* __restrict__ w2, float* __restrict__ h,
        float* __restrict__ e1, float* __restrict__ e2) {
    __shared__ float WT[64 * 65];
    __shared__ float zs[64];
    int t = threadIdx.x;
    int bn = blockIdx.x;                       // b*2000 + n
    for (int i = 0; i < 64; i++) WT[t * 65 + i] = W_in[i * 64 + t];  // WT[c][h]
    zs[t] = z[bn * 64 + t];
    __syncthreads();
    float acc = b_in[t];
    #pragma unroll
    for (int c = 0; c < 64; c++) acc += zs[c] * WT[c * 65 + t];
    float hv = fmaxf(acc, 0.0f);
    h[bn * 64 + t] = hv;
    float p1 = hv * w1[t], p2 = hv * w2[t];
    #pragma unroll
    for (int off = 32; off > 0; off >>= 1) {
        p1 += __shfl_down(p1, off);
        p2 += __shfl_down(p2, off);
    }
    if (t == 0) { e1[bn] = p1; e2[bn] = p2; }
}

// ---------------------------------------------------------------------------
// A = softmax(relu(emb @ emb^T), axis=1) -> bf16, zero-padded to 2048x2048
// ---------------------------------------------------------------------------
__global__ __launch_bounds__(256) void k_A(const float* __restrict__ emb,
                                           bf16* __restrict__ A) {
    int i = blockIdx.x, t = threadIdx.x;
    if (i >= NN) {
        for (int j = t; j < NP; j += 256) A[(size_t)i * NP + j] = __float2bfloat16(0.0f);
        return;
    }
    __shared__ float ei[DD];
    __shared__ float rowbuf[NP];
    __shared__ float red[256];
    if (t < DD) ei[t] = emb[i * DD + t];
    __syncthreads();
    float lmax = -1e30f;
    for (int j = t; j < NP; j += 256) {
        float s = 0.0f;
        if (j < NN) {
            #pragma unroll
            for (int d = 0; d < DD; d++) s += ei[d] * emb[j * DD + d];
            s = fmaxf(s, 0.0f);
            lmax = fmaxf(lmax, s);
        }
        rowbuf[j] = s;
    }
    red[t] = lmax; __syncthreads();
    for (int o = 128; o > 0; o >>= 1) { if (t < o) red[t] = fmaxf(red[t], red[t + o]); __syncthreads(); }
    float mx = red[0];
    __syncthreads();
    float lsum = 0.0f;
    for (int j = t; j < NN; j += 256) {
        float e = __expf(rowbuf[j] - mx);
        rowbuf[j] = e; lsum += e;
    }
    red[t] = lsum; __syncthreads();
    for (int o = 128; o > 0; o >>= 1) { if (t < o) red[t] += red[t + o]; __syncthreads(); }
    float inv = 1.0f / red[0];
    for (int j = t; j < NP; j += 256)
        A[(size_t)i * NP + j] = __float2bfloat16(j < NN ? rowbuf[j] * inv : 0.0f);
}

// ---------------------------------------------------------------------------
// vs (2000x2000 f32) -> vs_bf (2048x2048 bf16, zero pad)
// ---------------------------------------------------------------------------
__global__ void k_cvt_vs(const float* __restrict__ vs, bf16* __restrict__ out) {
    int id = blockIdx.x * 256 + threadIdx.x;   // over NP*NP
    int n = id >> 11, m = id & (NP - 1);
    float v = (n < NN && m < NN) ? vs[n * NN + m] : 0.0f;
    out[id] = __float2bfloat16(v);
}

// ---------------------------------------------------------------------------
// transpose h: hTcat[b*64+c][n] = h[b][n][c]  (bf16, n-pad 0)
// also writes the k=0 half of hsT: hsT[b*128+c][n]
// grid (32 ntiles, 8 b), 256 thr, 64x64 LDS tile
// ---------------------------------------------------------------------------
__global__ __launch_bounds__(256) void k_hT(const float* __restrict__ h,
                                            bf16* __restrict__ hTcat,
                                            bf16* __restrict__ hsT) {
    __shared__ float tile[64 * 65];
    int nt = blockIdx.x, b = blockIdx.y;
    int tx = threadIdx.x & 63, ty = threadIdx.x >> 6;
    int n0 = nt * 64;
    for (int i = ty * 16; i < ty * 16 + 16; i++) {
        int n = n0 + i;
        tile[i * 65 + tx] = (n < NN) ? h[((size_t)b * NN + n) * 64 + tx] : 0.0f;
    }
    __syncthreads();
    for (int i = ty * 16; i < ty * 16 + 16; i++) {
        bf16 v = __float2bfloat16(tile[tx * 65 + i]);   // h[b][n0+tx][i]
        hTcat[((size_t)b * 64 + i) * NP + n0 + tx] = v;
        hsT[((size_t)b * 128 + i) * NP + n0 + tx] = v;
    }
}

// ---------------------------------------------------------------------------
// transpose Ahcat (2048x512 f32) into hsT k=1 half:
// hsT[b*128+64+c][p] = Ahcat[p][b*64+c]
// ---------------------------------------------------------------------------
__global__ __launch_bounds__(256) void k_AhT(const float* __restrict__ Ahcat,
                                             bf16* __restrict__ hsT) {
    __shared__ float tile[64 * 65];
    int pt = blockIdx.x, b = blockIdx.y;
    int tx = threadIdx.x & 63, ty = threadIdx.x >> 6;
    int p0 = pt * 64, q0 = b * 64;
    for (int i = ty * 16; i < ty * 16 + 16; i++)
        tile[i * 65 + tx] = Ahcat[((size_t)p0 + i) * 512 + q0 + tx];
    __syncthreads();
    for (int i = ty * 16; i < ty * 16 + 16; i++)
        hsT[((size_t)b * 128 + 64 + i) * NP + p0 + tx] =
            __float2bfloat16(tile[tx * 65 + i]);
}

// ---------------------------------------------------------------------------
// Tt[p][m] = sigmoid(e1[m]*e2[p] + bs[m][p]), bf16, zero pad. 64x64 tiles.
// ---------------------------------------------------------------------------
__global__ __launch_bounds__(256) void k_Tt(const float* __restrict__ e1,
                                            const float* __restrict__ e2,
                                            const float* __restrict__ bs,
                                            bf16* __restrict__ Tt) {
    __shared__ float tile[64 * 65];
    int mt = blockIdx.x, pt = blockIdx.y;
    int tx = threadIdx.x & 63, ty = threadIdx.x >> 6;
    int m0 = mt * 64, p0 = pt * 64;
    int p = p0 + tx;
    float e2v = (p < NN) ? e2[p] : 0.0f;
    for (int i = ty * 16; i < ty * 16 + 16; i++) {
        int m = m0 + i;
        float v = 0.0f;
        if (m < NN && p < NN)
            v = fast_sigmoid(e1[m] * e2v + bs[(size_t)m * NN + p]);
        tile[i * 65 + tx] = v;
    }
    __syncthreads();
    for (int i = ty * 16; i < ty * 16 + 16; i++)
        Tt[((size_t)p0 + i) * NP + m0 + tx] = __float2bfloat16(tile[tx * 65 + i]);
}

// ---------------------------------------------------------------------------
// row softmax of M (f32, 2048x2048, rows<2000 valid, cols<2000 valid) -> E bf16
// ---------------------------------------------------------------------------
__global__ __launch_bounds__(256) void k_smax(const float* __restrict__ M,
                                              bf16* __restrict__ E) {
    int n = blockIdx.x, t = threadIdx.x;
    if (n >= NN) {
        for (int j = t; j < NP; j += 256) E[(size_t)n * NP + j] = __float2bfloat16(0.0f);
        return;
    }
    __shared__ float rowbuf[NP];
    __shared__ float red[256];
    const float* row = M + (size_t)n * NP;
    float lmax = -1e30f;
    for (int j = t; j < NN; j += 256) lmax = fmaxf(lmax, row[j]);
    red[t] = lmax; __syncthreads();
    for (int o = 128; o > 0; o >>= 1) { if (t < o) red[t] = fmaxf(red[t], red[t + o]); __syncthreads(); }
    float mx = red[0];
    __syncthreads();
    float lsum = 0.0f;
    for (int j = t; j < NN; j += 256) {
        float e = __expf(row[j] - mx);
        rowbuf[j] = e; lsum += e;
    }
    red[t] = lsum; __syncthreads();
    for (int o = 128; o > 0; o >>= 1) { if (t < o) red[t] += red[t + o]; __syncthreads(); }
    float inv = 1.0f / red[0];
    for (int j = t; j < NP; j += 256)
        E[(size_t)n * NP + j] = __float2bfloat16(j < NN ? rowbuf[j] * inv : 0.0f);
}

// ---------------------------------------------------------------------------
// Generic bf16 MFMA GEMM: C[M][N] = X[M][K] @ Yt[N][K]^T, fp32 out.
// M,N multiples of 128; K multiple of 32; no bounds checks (pre-padded).
// 256 thr = 4 waves (2x2), each wave 64x64 = 4x4 mfma_f32_16x16x32_bf16.
// LDS row stride 40 (pad 8) -> fragment ds_read_b128 is 2-way (free).
// ---------------------------------------------------------------------------
#define LDK 40
__global__ __launch_bounds__(256) void k_gemm_bt(
        const bf16* __restrict__ X, const bf16* __restrict__ Yt,
        float* __restrict__ C, int K, int ldx, int ldy, int ldc,
        long long sX, long long sY, long long sC) {
    __shared__ short As[128 * LDK];
    __shared__ short Bs[128 * LDK];
    int z = blockIdx.z;
    const bf16* Xp = X + (long long)z * sX;
    const bf16* Yp = Yt + (long long)z * sY;
    float* Cp = C + (long long)z * sC;
    int tid = threadIdx.x;
    int m0 = blockIdx.x * 128, n0 = blockIdx.y * 128;
    int wave = tid >> 6, lane = tid & 63;
    int wm = (wave >> 1) * 64, wn = (wave & 1) * 64;
    int fr = lane & 15, kq = lane >> 4;

    f32x4 zero = {0.f, 0.f, 0.f, 0.f};
    f32x4 acc[4][4];
    #pragma unroll
    for (int i = 0; i < 4; i++)
        #pragma unroll
        for (int j = 0; j < 4; j++) acc[i][j] = zero;

    int r0 = tid >> 2,           c80 = (tid & 3) * 8;
    int r1 = (tid + 256) >> 2,   c81 = (tid & 3) * 8;   // (tid+256)&3 == tid&3

    for (int k0 = 0; k0 < K; k0 += 32) {
        bf16x8 xa0 = *(const bf16x8*)(Xp + (long long)(m0 + r0) * ldx + k0 + c80);
        bf16x8 xa1 = *(const bf16x8*)(Xp + (long long)(m0 + r1) * ldx + k0 + c81);
        bf16x8 yb0 = *(const bf16x8*)(Yp + (long long)(n0 + r0) * ldy + k0 + c80);
        bf16x8 yb1 = *(const bf16x8*)(Yp + (long long)(n0 + r1) * ldy + k0 + c81);
        __syncthreads();                      // prev iter's LDS reads done
        *(bf16x8*)(As + r0 * LDK + c80) = xa0;
        *(bf16x8*)(As + r1 * LDK + c81) = xa1;
        *(bf16x8*)(Bs + r0 * LDK + c80) = yb0;
        *(bf16x8*)(Bs + r1 * LDK + c81) = yb1;
        __syncthreads();
        bf16x8 a[4], b[4];
        #pragma unroll
        for (int i = 0; i < 4; i++)
            a[i] = *(const bf16x8*)(As + (wm + i * 16 + fr) * LDK + kq * 8);
        #pragma unroll
        for (int j = 0; j < 4; j++)
            b[j] = *(const bf16x8*)(Bs + (wn + j * 16 + fr) * LDK + kq * 8);
        #pragma unroll
        for (int i = 0; i < 4; i++)
            #pragma unroll
            for (int j = 0; j < 4; j++)
                acc[i][j] = __builtin_amdgcn_mfma_f32_16x16x32_bf16(a[i], b[j], acc[i][j], 0, 0, 0);
    }
    int rq = kq * 4;   // D: col = lane&15, row = (lane>>4)*4 + reg  [m89-verified]
    for (int i = 0; i < 4; i++)
        for (int j = 0; j < 4; j++)
            #pragma unroll
            for (int r = 0; r < 4; r++) {
                int row = m0 + wm + i * 16 + rq + r;
                int col = n0 + wn + j * 16 + fr;
                Cp[(long long)row * ldc + col] = acc[i][j][r];
            }
}

// ---------------------------------------------------------------------------
// g[b][n][o] = bias_n[o] + sum_j xg[b][n][j] * Wn[j][o]
// Wn[j=k*64+i][o] = sum_d emb[n][d] * wp[d][k][i][o]; bias_n = emb[n] @ bp
// one block per n, all 8 batches.
// ---------------------------------------------------------------------------
__global__ __launch_bounds__(256) void k_g(
        const float* __restrict__ emb, const float* __restrict__ wp,
        const float* __restrict__ bp, const float* __restrict__ xg,
        float* __restrict__ g) {
    __shared__ float Wn[8192];       // [j][o]
    __shared__ float xgs[1024];      // [b][j]
    __shared__ float embs[16];
    __shared__ float biass[64];
    int n = blockIdx.x, t = threadIdx.x;
    if (t < 16) embs[t] = emb[n * 16 + t];
    __syncthreads();
    for (int s = 0; s < 32; s++) {
        int e = t + s * 256;
        int j = e >> 6, o = e & 63;
        int kk = j >> 6, ii = j & 63;
        float a = 0.f;
        #pragma unroll
        for (int d = 0; d < 16; d++)
            a += embs[d] * wp[(((size_t)d * 2 + kk) * 64 + ii) * 64 + o];
        Wn[e] = a;
    }
    if (t < 64) {
        float a = 0.f;
        #pragma unroll
        for (int d = 0; d < 16; d++) a += embs[d] * bp[d * 64 + t];
        biass[t] = a;
    }
    for (int s = 0; s < 4; s++) {
        int id = t + s * 256;
        int b = id >> 7, j = id & 127;
        xgs[id] = xg[((size_t)b * NP + n) * 128 + j];
    }
    __syncthreads();
    int o = t & 63, bh = t >> 6;
    for (int half = 0; half < 2; half++) {
        int b = bh + half * 4;
        float a = biass[o];
        for (int j = 0; j < 128; j++) a += xgs[b * 128 + j] * Wn[j * 64 + o];
        g[((size_t)b * NN + n) * 64 + o] = a;
    }
}

// ---------------------------------------------------------------------------
// out[b][n][o] = 0.1*tanh(b_out[o] + sum_h W_out[o][h]*g[b][n][h])
// one block per n, all 8 batches (W_out reuse x8).
// ---------------------------------------------------------------------------
__global__ __launch_bounds__(256) void k_out(
        const float* __restrict__ g, const float* __restrict__ W_out,
        const float* __restrict__ b_out, float* __restrict__ out) {
    __shared__ float gs[8 * 64];
    int n = blockIdx.x, t = threadIdx.x;
    for (int s = 0; s < 2; s++) {
        int id = t + s * 256;
        int b = id >> 6, hh = id & 63;
        gs[id] = g[((size_t)b * NN + n) * 64 + hh];
    }
    __syncthreads();
    for (int s = 0; s < 16; s++) {
        int o = t + s * 256;
        const float4* wr4 = (const float4*)(W_out + (size_t)o * 64);
        float acc[8];
        float bo = b_out[o];
        #pragma unroll
        for (int b = 0; b < 8; b++) acc[b] = bo;
        #pragma unroll 4
        for (int h4 = 0; h4 < 16; h4++) {
            float4 w = wr4[h4];
            #pragma unroll
            for (int b = 0; b < 8; b++) {
                const float* gb = gs + b * 64 + h4 * 4;
                acc[b] += w.x * gb[0] + w.y * gb[1] + w.z * gb[2] + w.w * gb[3];
            }
        }
        #pragma unroll
        for (int b = 0; b < 8; b++)
            out[((size_t)b * NN + n) * 4096 + o] = 0.1f * fast_tanh(acc[b]);
    }
}

// ---------------------------------------------------------------------------
extern "C" void kernel_launch(void* const* d_in, const int* in_sizes, int n_in,
                              void* d_out, int out_size, void* d_ws, size_t ws_size,
                              hipStream_t stream) {
    const float* z     = (const float*)d_in[0];
    const float* W_in  = (const float*)d_in[1];
    const float* b_in  = (const float*)d_in[2];
    const float* W_out = (const float*)d_in[3];
    const float* b_out = (const float*)d_in[4];
    const float* emb   = (const float*)d_in[5];
    const float* wp    = (const float*)d_in[6];
    const float* bp    = (const float*)d_in[7];
    const float* w1    = (const float*)d_in[8];
    const float* w2    = (const float*)d_in[9];
    const float* vs    = (const float*)d_in[10];
    const float* bs    = (const float*)d_in[11];

    char* p = (char*)d_ws;
    auto alloc = [&](size_t bytes) -> char* {
        char* r = p;
        p += (bytes + 255) & ~(size_t)255;
        return r;
    };
    float* h     = (float*)alloc((size_t)BB * NN * 64 * 4);      // 4.1 MB
    float* e1    = (float*)alloc((size_t)BB * NN * 4);
    float* e2    = (float*)alloc((size_t)BB * NN * 4);
    bf16*  A_bf  = (bf16*) alloc((size_t)NP * NP * 2);           // 8.4 MB
    bf16*  vs_bf = (bf16*) alloc((size_t)NP * NP * 2);           // 8.4 MB
    bf16*  Tt    = (bf16*) alloc((size_t)NP * NP * 2);           // 8.4 MB (per-batch reuse)
    float* Mbuf  = (float*)alloc((size_t)NP * NP * 4);           // 16.8 MB (per-batch reuse)
    bf16*  hTcat = (bf16*) alloc((size_t)512 * NP * 2);          // 2.1 MB
    float* Ahcat = (float*)alloc((size_t)NP * 512 * 4);          // 4.2 MB
    bf16*  hsT   = (bf16*) alloc((size_t)BB * 128 * NP * 2);     // 4.2 MB
    float* xg    = (float*)alloc((size_t)BB * NP * 128 * 4);     // 8.4 MB
    float* g     = (float*)alloc((size_t)BB * NN * 64 * 4);      // 4.1 MB
    // E (bf16, 8x2048x2048 = 67 MB) lives in d_out (262 MB), overwritten last.
    bf16* E_all = (bf16*)d_out;

    k_h<<<BB * NN, 64, 0, stream>>>(z, W_in, b_in, w1, w2, h, e1, e2);
    k_A<<<NP, 256, 0, stream>>>(emb, A_bf);
    k_cvt_vs<<<(NP * NP) / 256, 256, 0, stream>>>(vs, vs_bf);
    k_hT<<<dim3(NP / 64, BB), 256, 0, stream>>>(h, hTcat, hsT);
    // Ahcat[n][b*64+c] = sum_m A[n][m] h[b][m][c]
    k_gemm_bt<<<dim3(16, 4, 1), 256, 0, stream>>>(A_bf, hTcat, Ahcat,
                                                  NP, NP, NP, 512, 0, 0, 0);
    k_AhT<<<dim3(NP / 64, BB), 256, 0, stream>>>(Ahcat, hsT);

    for (int b = 0; b < BB; b++) {
        k_Tt<<<dim3(NP / 64, NP / 64), 256, 0, stream>>>(e1 + b * NN, e2 + b * NN, bs, Tt);
        // M[n][p] = sum_m vs[n][m] * T[m][p]
        k_gemm_bt<<<dim3(16, 16, 1), 256, 0, stream>>>(vs_bf, Tt, Mbuf,
                                                       NP, NP, NP, NP, 0, 0, 0);
        k_smax<<<NP, 256, 0, stream>>>(Mbuf, E_all + (size_t)b * NP * NP);
    }
    // xg[b][n][j] = sum_p E[b][n][p] * hsT[b][j][p]   (batched over z)
    k_gemm_bt<<<dim3(16, 1, BB), 256, 0, stream>>>(E_all, hsT, xg,
                                                   NP, NP, NP, 128,
                                                   (long long)NP * NP,
                                                   (long long)128 * NP,
                                                   (long long)NP * 128);
    k_g<<<NN, 256, 0, stream>>>(emb, wp, bp, xg, g);
    k_out<<<NN, 256, 0, stream>>>(g, W_out, b_out, (float*)d_out);
}

// Round 2
// 1057.664 us; speedup vs baseline: 1.2353x; 1.2353x over previous
//
#include <hip/hip_runtime.h>
#include <hip/hip_bf16.h>

#define NN 2000   // nodes
#define NP 2048   // padded
#define BB 8
#define HH 64
#define DD 16

typedef __hip_bfloat16 bf16;
typedef short bf16x8 __attribute__((ext_vector_type(8)));  // 8 bf16 in 4 VGPRs
typedef float f32x4 __attribute__((ext_vector_type(4)));

__device__ __forceinline__ float fast_sigmoid(float x) {
    return 1.0f / (1.0f + __expf(-x));
}
__device__ __forceinline__ float fast_tanh(float x) {
    float e = __expf(2.0f * x);           // inf-safe: x>>0 -> 1, x<<0 -> -1
    return 1.0f - 2.0f / (e + 1.0f);
}

// async 16B global->LDS. LDS dest = wave-uniform base + lane*16 (m97/m104).
__device__ __forceinline__ void glds16(const void* g, void* l) {
    __builtin_amdgcn_global_load_lds(
        (const __attribute__((address_space(1))) void*)g,
        (__attribute__((address_space(3))) void*)l, 16, 0, 0);
}

// ---------------------------------------------------------------------------
// h = relu(z @ W_in^T + b_in); e1 = h@w1, e2 = h@w2.  One 64-thread wave per
// (b,n) row. W_in staged transposed in LDS (pad 65 -> conflict-free).
// ---------------------------------------------------------------------------
__global__ __launch_bounds__(64) void k_h(
        const float* __restrict__ z, const float* __restrict__ W_in,
        const float* __restrict__ b_in, const float* __restrict__ w1,
        const float* __restrict__ w2, float* __restrict__ h,
        float* __restrict__ e1, float* __restrict__ e2) {
    __shared__ float WT[64 * 65];
    __shared__ float zs[64];
    int t = threadIdx.x;
    int bn = blockIdx.x;                       // b*2000 + n
    for (int i = 0; i < 64; i++) WT[t * 65 + i] = W_in[i * 64 + t];  // WT[c][h]
    zs[t] = z[bn * 64 + t];
    __syncthreads();
    float acc = b_in[t];
    #pragma unroll
    for (int c = 0; c < 64; c++) acc += zs[c] * WT[c * 65 + t];
    float hv = fmaxf(acc, 0.0f);
    h[bn * 64 + t] = hv;
    float p1 = hv * w1[t], p2 = hv * w2[t];
    #pragma unroll
    for (int off = 32; off > 0; off >>= 1) {
        p1 += __shfl_down(p1, off);
        p2 += __shfl_down(p2, off);
    }
    if (t == 0) { e1[bn] = p1; e2[bn] = p2; }
}

// ---------------------------------------------------------------------------
// A = softmax(relu(emb @ emb^T), axis=1) -> bf16, zero-padded to 2048x2048
// ---------------------------------------------------------------------------
__global__ __launch_bounds__(256) void k_A(const float* __restrict__ emb,
                                           bf16* __restrict__ A) {
    int i = blockIdx.x, t = threadIdx.x;
    if (i >= NN) {
        for (int j = t; j < NP; j += 256) A[(size_t)i * NP + j] = __float2bfloat16(0.0f);
        return;
    }
    __shared__ float ei[DD];
    __shared__ float rowbuf[NP];
    __shared__ float red[256];
    if (t < DD) ei[t] = emb[i * DD + t];
    __syncthreads();
    float lmax = -1e30f;
    for (int j = t; j < NP; j += 256) {
        float s = 0.0f;
        if (j < NN) {
            #pragma unroll
            for (int d = 0; d < DD; d++) s += ei[d] * emb[j * DD + d];
            s = fmaxf(s, 0.0f);
            lmax = fmaxf(lmax, s);
        }
        rowbuf[j] = s;
    }
    red[t] = lmax; __syncthreads();
    for (int o = 128; o > 0; o >>= 1) { if (t < o) red[t] = fmaxf(red[t], red[t + o]); __syncthreads(); }
    float mx = red[0];
    __syncthreads();
    float lsum = 0.0f;
    for (int j = t; j < NN; j += 256) {
        float e = __expf(rowbuf[j] - mx);
        rowbuf[j] = e; lsum += e;
    }
    red[t] = lsum; __syncthreads();
    for (int o = 128; o > 0; o >>= 1) { if (t < o) red[t] += red[t + o]; __syncthreads(); }
    float inv = 1.0f / red[0];
    for (int j = t; j < NP; j += 256)
        A[(size_t)i * NP + j] = __float2bfloat16(j < NN ? rowbuf[j] * inv : 0.0f);
}

// ---------------------------------------------------------------------------
// vs (2000x2000 f32) -> vs_bf (2048x2048 bf16, zero pad)
// ---------------------------------------------------------------------------
__global__ void k_cvt_vs(const float* __restrict__ vs, bf16* __restrict__ out) {
    int id = blockIdx.x * 256 + threadIdx.x;   // over NP*NP
    int n = id >> 11, m = id & (NP - 1);
    float v = (n < NN && m < NN) ? vs[n * NN + m] : 0.0f;
    out[id] = __float2bfloat16(v);
}

// W_out (4096x64 f32) -> bf16
__global__ void k_cvt_wout(const float* __restrict__ W_out, bf16* __restrict__ out) {
    int id = blockIdx.x * 256 + threadIdx.x;   // 4096*64
    out[id] = __float2bfloat16(W_out[id]);
}

// ---------------------------------------------------------------------------
// transpose h: hTcat[b*64+c][n] = h[b][n][c]  (bf16, n-pad 0)
// also writes the k=0 half of hsT: hsT[b*128+c][n]
// ---------------------------------------------------------------------------
__global__ __launch_bounds__(256) void k_hT(const float* __restrict__ h,
                                            bf16* __restrict__ hTcat,
                                            bf16* __restrict__ hsT) {
    __shared__ float tile[64 * 65];
    int nt = blockIdx.x, b = blockIdx.y;
    int tx = threadIdx.x & 63, ty = threadIdx.x >> 6;
    int n0 = nt * 64;
    for (int i = ty * 16; i < ty * 16 + 16; i++) {
        int n = n0 + i;
        tile[i * 65 + tx] = (n < NN) ? h[((size_t)b * NN + n) * 64 + tx] : 0.0f;
    }
    __syncthreads();
    for (int i = ty * 16; i < ty * 16 + 16; i++) {
        bf16 v = __float2bfloat16(tile[tx * 65 + i]);   // h[b][n0+tx][i]
        hTcat[((size_t)b * 64 + i) * NP + n0 + tx] = v;
        hsT[((size_t)b * 128 + i) * NP + n0 + tx] = v;
    }
}

// ---------------------------------------------------------------------------
// transpose Ahcat (2048x512 f32) into hsT k=1 half:
// hsT[b*128+64+c][p] = Ahcat[p][b*64+c]
// ---------------------------------------------------------------------------
__global__ __launch_bounds__(256) void k_AhT(const float* __restrict__ Ahcat,
                                             bf16* __restrict__ hsT) {
    __shared__ float tile[64 * 65];
    int pt = blockIdx.x, b = blockIdx.y;
    int tx = threadIdx.x & 63, ty = threadIdx.x >> 6;
    int p0 = pt * 64, q0 = b * 64;
    for (int i = ty * 16; i < ty * 16 + 16; i++)
        tile[i * 65 + tx] = Ahcat[((size_t)p0 + i) * 512 + q0 + tx];
    __syncthreads();
    for (int i = ty * 16; i < ty * 16 + 16; i++)
        hsT[((size_t)b * 128 + 64 + i) * NP + p0 + tx] =
            __float2bfloat16(tile[tx * 65 + i]);
}

// ---------------------------------------------------------------------------
// Tt[p][m] = sigmoid(e1[m]*e2[p] + bs[m][p]), bf16, zero pad. 64x64 tiles.
// ---------------------------------------------------------------------------
__global__ __launch_bounds__(256) void k_Tt(const float* __restrict__ e1,
                                            const float* __restrict__ e2,
                                            const float* __restrict__ bs,
                                            bf16* __restrict__ Tt) {
    __shared__ float tile[64 * 65];
    int mt = blockIdx.x, pt = blockIdx.y;
    int tx = threadIdx.x & 63, ty = threadIdx.x >> 6;
    int m0 = mt * 64, p0 = pt * 64;
    int p = p0 + tx;
    float e2v = (p < NN) ? e2[p] : 0.0f;
    for (int i = ty * 16; i < ty * 16 + 16; i++) {
        int m = m0 + i;
        float v = 0.0f;
        if (m < NN && p < NN)
            v = fast_sigmoid(e1[m] * e2v + bs[(size_t)m * NN + p]);
        tile[i * 65 + tx] = v;
    }
    __syncthreads();
    for (int i = ty * 16; i < ty * 16 + 16; i++)
        Tt[((size_t)p0 + i) * NP + m0 + tx] = __float2bfloat16(tile[tx * 65 + i]);
}

// ---------------------------------------------------------------------------
// row softmax of M (f32, 2048x2048, rows<2000 valid, cols<2000 valid) -> E bf16
// ---------------------------------------------------------------------------
__global__ __launch_bounds__(256) void k_smax(const float* __restrict__ M,
                                              bf16* __restrict__ E) {
    int n = blockIdx.x, t = threadIdx.x;
    if (n >= NN) {
        for (int j = t; j < NP; j += 256) E[(size_t)n * NP + j] = __float2bfloat16(0.0f);
        return;
    }
    __shared__ float rowbuf[NP];
    __shared__ float red[256];
    const float* row = M + (size_t)n * NP;
    float lmax = -1e30f;
    for (int j = t; j < NN; j += 256) lmax = fmaxf(lmax, row[j]);
    red[t] = lmax; __syncthreads();
    for (int o = 128; o > 0; o >>= 1) { if (t < o) red[t] = fmaxf(red[t], red[t + o]); __syncthreads(); }
    float mx = red[0];
    __syncthreads();
    float lsum = 0.0f;
    for (int j = t; j < NN; j += 256) {
        float e = __expf(row[j] - mx);
        rowbuf[j] = e; lsum += e;
    }
    red[t] = lsum; __syncthreads();
    for (int o = 128; o > 0; o >>= 1) { if (t < o) red[t] += red[t + o]; __syncthreads(); }
    float inv = 1.0f / red[0];
    for (int j = t; j < NP; j += 256)
        E[(size_t)n * NP + j] = __float2bfloat16(j < NN ? rowbuf[j] * inv : 0.0f);
}

// ---------------------------------------------------------------------------
// bf16 MFMA GEMM: C[M][N] = X[M][K] @ Yt[N][K]^T, fp32 out (optional
// bias+tanh epilogue). M,N mult of 128; K mult of 32; no bounds checks.
// 256 thr = 4 waves (2x2), each wave 64x64 = 4x4 mfma_f32_16x16x32_bf16.
// Staging: global_load_lds 16B (m97 structure) -> UNPADDED LDS, row stride
// 32 shorts (64B). Fragment ds_read_b128: 8 lanes per 4-bank group = minimum
// uniform distribution for a 1024B wave read -> effectively conflict-free.
// ---------------------------------------------------------------------------
template<bool TANH>
__global__ __launch_bounds__(256) void k_gemm_bt(
        const bf16* __restrict__ X, const bf16* __restrict__ Yt,
        float* __restrict__ C, const float* __restrict__ bias,
        int K, int ldx, int ldy, int ldc,
        long long sX, long long sY, long long sC) {
    __shared__ short As[128 * 32];
    __shared__ short Bs[128 * 32];
    int z = blockIdx.z;
    const bf16* Xp = X + (long long)z * sX;
    const bf16* Yp = Yt + (long long)z * sY;
    float* Cp = C + (long long)z * sC;
    int tid = threadIdx.x;
    int m0 = blockIdx.x * 128, n0 = blockIdx.y * 128;
    int wave = tid >> 6, lane = tid & 63;
    int wm = (wave >> 1) * 64, wn = (wave & 1) * 64;
    int fr = lane & 15, kq = lane >> 4;

    f32x4 zero = {0.f, 0.f, 0.f, 0.f};
    f32x4 acc[4][4];
    #pragma unroll
    for (int i = 0; i < 4; i++)
        #pragma unroll
        for (int j = 0; j < 4; j++) acc[i][j] = zero;

    // staging source/dest: wave w, lane l covers row w*16 + l/4 (+64 for the
    // second issue), 8 shorts starting at (l%4)*8. LDS dest = base + lane*16B.
    int lrow = lane >> 2, lcol = (lane & 3) * 8;
    const bf16* xg0 = Xp + (long long)(m0 + wave * 16 + lrow) * ldx + lcol;
    const bf16* xg1 = xg0 + (long long)64 * ldx;
    const bf16* yg0 = Yp + (long long)(n0 + wave * 16 + lrow) * ldy + lcol;
    const bf16* yg1 = yg0 + (long long)64 * ldy;
    short* lA0 = As + wave * 512;          // rows wave*16..+15
    short* lA1 = As + (wave + 4) * 512;    // rows 64+wave*16..+15
    short* lB0 = Bs + wave * 512;
    short* lB1 = Bs + (wave + 4) * 512;

    for (int k0 = 0; k0 < K; k0 += 32) {
        __syncthreads();                   // prev iter's LDS reads done
        glds16(xg0 + k0, lA0);
        glds16(xg1 + k0, lA1);
        glds16(yg0 + k0, lB0);
        glds16(yg1 + k0, lB1);
        __syncthreads();                   // vmcnt(0) drained by compiler
        bf16x8 a[4], b[4];
        #pragma unroll
        for (int i = 0; i < 4; i++)
            a[i] = *(const bf16x8*)(As + (wm + i * 16 + fr) * 32 + kq * 8);
        #pragma unroll
        for (int j = 0; j < 4; j++)
            b[j] = *(const bf16x8*)(Bs + (wn + j * 16 + fr) * 32 + kq * 8);
        #pragma unroll
        for (int i = 0; i < 4; i++)
            #pragma unroll
            for (int j = 0; j < 4; j++)
                acc[i][j] = __builtin_amdgcn_mfma_f32_16x16x32_bf16(a[i], b[j], acc[i][j], 0, 0, 0);
    }
    int rq = kq * 4;   // D: col = lane&15, row = (lane>>4)*4 + reg  [m89-verified]
    for (int i = 0; i < 4; i++)
        for (int j = 0; j < 4; j++) {
            int col = n0 + wn + j * 16 + fr;
            float bv = TANH ? bias[col] : 0.0f;
            #pragma unroll
            for (int r = 0; r < 4; r++) {
                int row = m0 + wm + i * 16 + rq + r;
                float v = acc[i][j][r];
                Cp[(long long)row * ldc + col] =
                    TANH ? 0.1f * fast_tanh(v + bv) : v;
            }
        }
}

// ---------------------------------------------------------------------------
// g[b][n][o] = bias_n[o] + sum_j xg[b][n][j] * Wn[j][o]   (bf16 out)
// Wn[j=k*64+i][o] = sum_d emb[n][d] * wp[d][k][i][o]; bias_n = emb[n] @ bp
// one block per n, all 8 batches.
// ---------------------------------------------------------------------------
__global__ __launch_bounds__(256) void k_g(
        const float* __restrict__ emb, const float* __restrict__ wp,
        const float* __restrict__ bp, const float* __restrict__ xg,
        bf16* __restrict__ gbf) {
    __shared__ float Wn[8192];       // [j][o]
    __shared__ float xgs[1024];      // [b][j]
    __shared__ float embs[16];
    __shared__ float biass[64];
    int n = blockIdx.x, t = threadIdx.x;
    if (t < 16) embs[t] = emb[n * 16 + t];
    __syncthreads();
    for (int s = 0; s < 32; s++) {
        int e = t + s * 256;
        int j = e >> 6, o = e & 63;
        int kk = j >> 6, ii = j & 63;
        float a = 0.f;
        #pragma unroll
        for (int d = 0; d < 16; d++)
            a += embs[d] * wp[(((size_t)d * 2 + kk) * 64 + ii) * 64 + o];
        Wn[e] = a;
    }
    if (t < 64) {
        float a = 0.f;
        #pragma unroll
        for (int d = 0; d < 16; d++) a += embs[d] * bp[d * 64 + t];
        biass[t] = a;
    }
    for (int s = 0; s < 4; s++) {
        int id = t + s * 256;
        int b = id >> 7, j = id & 127;
        xgs[id] = xg[((size_t)b * NP + n) * 128 + j];
    }
    __syncthreads();
    int o = t & 63, bh = t >> 6;
    for (int half = 0; half < 2; half++) {
        int b = bh + half * 4;
        float a = biass[o];
        for (int j = 0; j < 128; j++) a += xgs[b * 128 + j] * Wn[j * 64 + o];
        gbf[((size_t)b * NN + n) * 64 + o] = __float2bfloat16(a);
    }
}

// ---------------------------------------------------------------------------
extern "C" void kernel_launch(void* const* d_in, const int* in_sizes, int n_in,
                              void* d_out, int out_size, void* d_ws, size_t ws_size,
                              hipStream_t stream) {
    const float* z     = (const float*)d_in[0];
    const float* W_in  = (const float*)d_in[1];
    const float* b_in  = (const float*)d_in[2];
    const float* W_out = (const float*)d_in[3];
    const float* b_out = (const float*)d_in[4];
    const float* emb   = (const float*)d_in[5];
    const float* wp    = (const float*)d_in[6];
    const float* bp    = (const float*)d_in[7];
    const float* w1    = (const float*)d_in[8];
    const float* w2    = (const float*)d_in[9];
    const float* vs    = (const float*)d_in[10];
    const float* bs    = (const float*)d_in[11];

    char* p = (char*)d_ws;
    auto alloc = [&](size_t bytes) -> char* {
        char* r = p;
        p += (bytes + 255) & ~(size_t)255;
        return r;
    };
    float* h     = (float*)alloc((size_t)BB * NN * 64 * 4);      // 4.1 MB
    float* e1    = (float*)alloc((size_t)BB * NN * 4);
    float* e2    = (float*)alloc((size_t)BB * NN * 4);
    bf16*  A_bf  = (bf16*) alloc((size_t)NP * NP * 2);           // 8.4 MB
    bf16*  vs_bf = (bf16*) alloc((size_t)NP * NP * 2);           // 8.4 MB
    bf16*  Tt    = (bf16*) alloc((size_t)NP * NP * 2);           // 8.4 MB (per-batch reuse)
    float* Mbuf  = (float*)alloc((size_t)NP * NP * 4);           // 16.8 MB (per-batch reuse)
    bf16*  hTcat = (bf16*) alloc((size_t)512 * NP * 2);          // 2.1 MB
    float* Ahcat = (float*)alloc((size_t)NP * 512 * 4);          // 4.2 MB
    bf16*  hsT   = (bf16*) alloc((size_t)BB * 128 * NP * 2);     // 4.2 MB
    float* xg    = (float*)alloc((size_t)BB * NP * 128 * 4);     // 8.4 MB
    bf16*  gbf   = (bf16*) alloc((size_t)BB * NN * 64 * 2);      // 2.0 MB
    bf16*  Wo_bf = (bf16*) alloc((size_t)4096 * 64 * 2);         // 0.5 MB
    // E (bf16, 8x2048x2048 = 67 MB) lives in d_out (262 MB), overwritten last.
    bf16* E_all = (bf16*)d_out;

    k_h<<<BB * NN, 64, 0, stream>>>(z, W_in, b_in, w1, w2, h, e1, e2);
    k_A<<<NP, 256, 0, stream>>>(emb, A_bf);
    k_cvt_vs<<<(NP * NP) / 256, 256, 0, stream>>>(vs, vs_bf);
    k_cvt_wout<<<(4096 * 64) / 256, 256, 0, stream>>>(W_out, Wo_bf);
    k_hT<<<dim3(NP / 64, BB), 256, 0, stream>>>(h, hTcat, hsT);
    // Ahcat[n][b*64+c] = sum_m A[n][m] h[b][m][c]
    k_gemm_bt<false><<<dim3(16, 4, 1), 256, 0, stream>>>(A_bf, hTcat, Ahcat, nullptr,
                                                         NP, NP, NP, 512, 0, 0, 0);
    k_AhT<<<dim3(NP / 64, BB), 256, 0, stream>>>(Ahcat, hsT);

    for (int b = 0; b < BB; b++) {
        k_Tt<<<dim3(NP / 64, NP / 64), 256, 0, stream>>>(e1 + b * NN, e2 + b * NN, bs, Tt);
        // M[n][p] = sum_m vs[n][m] * T[m][p]
        k_gemm_bt<false><<<dim3(16, 16, 1), 256, 0, stream>>>(vs_bf, Tt, Mbuf, nullptr,
                                                              NP, NP, NP, NP, 0, 0, 0);
        k_smax<<<NP, 256, 0, stream>>>(Mbuf, E_all + (size_t)b * NP * NP);
    }
    // xg[b][n][j] = sum_p E[b][n][p] * hsT[b][j][p]   (batched over z)
    k_gemm_bt<false><<<dim3(16, 1, BB), 256, 0, stream>>>(E_all, hsT, xg, nullptr,
                                                          NP, NP, NP, 128,
                                                          (long long)NP * NP,
                                                          (long long)128 * NP,
                                                          (long long)NP * 128);
    k_g<<<NN, 256, 0, stream>>>(emb, wp, bp, xg, gbf);
    // out[bn][o] = 0.1*tanh(g[bn] . W_out[o] + b_out[o]);  16000 = 125*128
    k_gemm_bt<true><<<dim3(125, 32, 1), 256, 0, stream>>>(gbf, Wo_bf, (float*)d_out,
                                                          b_out, 64, 64, 64, 4096,
                                                          0, 0, 0);
}